// Round 6
// baseline (437.497 us; speedup 1.0000x reference)
//
#include <hip/hip_runtime.h>
#include <math.h>

// ws layout (floats):
//   esq   : [4096]
//   state : [64*8192]   f_rest, channel-major [b][c][yx]  (== f layout)
//   fhat  : [64*8192]   [b][c][yx]
//   z     : [16384][32] pair=(v<<6|b) rows
//   psc   : [131072]    pair*NCB+cb
//   pix   : [131072] int
#define WS_ESQ   0
#define WS_STATE 4096
#define WS_FHAT  (4096 + 524288)
#define WS_Z     (4096 + 2*524288)
#define WS_PSC   (4096 + 3*524288)
#define WS_PIX   (4096 + 3*524288 + 131072)

__device__ __forceinline__ float4 v4add(float4 a, float4 b) {
    return make_float4(__fadd_rn(a.x,b.x), __fadd_rn(a.y,b.y),
                       __fadd_rn(a.z,b.z), __fadd_rn(a.w,b.w));
}
__device__ __forceinline__ float4 v4sq(float4 a) {
    return make_float4(__fmul_rn(a.x,a.x), __fmul_rn(a.y,a.y),
                       __fmul_rn(a.z,a.z), __fmul_rn(a.w,a.w));
}
// numpy pairwise sum of 32 pre-rounded squares held in 8 float4s
__device__ __forceinline__ float np_pw32(float4 q0, float4 q1, float4 q2, float4 q3,
                                         float4 q4, float4 q5, float4 q6, float4 q7) {
    float4 rA = v4add(v4add(v4add(q0, q2), q4), q6);   // r[0..3]
    float4 rB = v4add(v4add(v4add(q1, q3), q5), q7);   // r[4..7]
    float l = __fadd_rn(__fadd_rn(rA.x, rA.y), __fadd_rn(rA.z, rA.w));
    float h = __fadd_rn(__fadd_rn(rB.x, rB.y), __fadd_rn(rB.z, rB.w));
    return __fadd_rn(l, h);
}

__device__ __forceinline__ double keys64(double x) {
    // jax keys cubic (a=-0.5)
    if (x < 1.0)      return ((1.5*x - 2.5)*x)*x + 1.0;
    else if (x < 2.0) return ((-0.5*x + 2.5)*x - 4.0)*x + 2.0;
    return 0.0;
}

// Apply kernel: 512 WGs = 64 b x 8 channel-slices of 4 (+16 esq WGs at s0).
// Combine prev partial argmins (2-stage, contiguous-ascending = first-index),
// gather h slice, bicubic-apply, persist state/fhat (channel-major), pool,
// write z rows. All fp32 sequences bit-identical to validated round-6 kernel.
__global__ __launch_bounds__(256) void vq_apply(
    const float* __restrict__ f, const float* __restrict__ emb,
    float* __restrict__ esq, float* __restrict__ state, float* __restrict__ fhat,
    float* __restrict__ zws, const float* __restrict__ psc, const int* __restrict__ pix,
    int sIdx, int pn, int pnPrev, int ncbPrev)
{
    __shared__ float fr[1280];      // f_rest slice [yx*5+cc]
    __shared__ float hs[676];       // h slice [v*4+cc]
    __shared__ int   idx_arr[176];
    __shared__ float U[256];        // bicubic weights [out][in], fp64->fp32 like jax
    __shared__ float red_f[1360];
    __shared__ int   red_i[1360];

    const int tid = threadIdx.x;
    const int wg  = blockIdx.x;
    if (wg >= 512) {                // s0 only: esq WGs
        int j = ((wg - 512) << 8) + tid;
        const float4* e4 = (const float4*)(emb + (size_t)j*32);
        esq[j] = np_pw32(v4sq(e4[0]),v4sq(e4[1]),v4sq(e4[2]),v4sq(e4[3]),
                         v4sq(e4[4]),v4sq(e4[5]),v4sq(e4[6]),v4sq(e4[7]));
        return;
    }
    const int b  = wg >> 3;
    const int c0 = (wg & 7) * 4;

    // ---- P1: load f_rest slice (channel-major, coalesced) ----
    const float* src = (sIdx <= 1) ? f : state;      // s0 never writes state: same layout
    for (int o = tid; o < 1024; o += 256) {
        int cc = o >> 8, yx = o & 255;
        fr[yx*5 + cc] = src[b*8192 + (c0 + cc)*256 + yx];
    }
    __syncthreads();

    if (sIdx > 0) {
        const int Vp = pnPrev * pnPrev;
        // ---- P2: combine prev partials, 2-stage (both contiguous ascending j) ----
        const int step = ncbPrev >> 3;
        for (int t = tid; t < Vp*8; t += 256) {
            int v = t >> 3, k = t & 7;
            const size_t base = (size_t)((v << 6) + b) * ncbPrev;
            float best = INFINITY; int bi = 0;
            for (int ch = k*step; ch < (k+1)*step; ++ch) {
                float sc = psc[base + ch];
                if (sc < best) { best = sc; bi = pix[base + ch]; }
            }
            red_f[t] = best; red_i[t] = bi;
        }
        __syncthreads();
        if (tid < Vp) {
            float best = INFINITY; int bi = 0;
            for (int k = 0; k < 8; ++k) {
                float sc = red_f[tid*8 + k];
                if (sc < best) { best = sc; bi = red_i[tid*8 + k]; }
            }
            idx_arr[tid] = bi;
        }
        __syncthreads();
        // ---- P3: gather h slice ----
        for (int t = tid; t < Vp*4; t += 256)
            hs[t] = emb[(size_t)idx_arr[t >> 2]*32 + c0 + (t & 3)];
        // ---- P4: bicubic weights in fp64 exactly like jax ----
        if (tid < 16) {
            double scl = 16.0 / (double)pnPrev;
            double inv = 1.0 / scl;
            double sp = ((double)tid + 0.5) * inv - 0.5;
            double w64[16]; double tot = 0.0;
            for (int q = 0; q < pnPrev; ++q) {
                double wv = keys64(fabs(sp - (double)q));
                w64[q] = wv; tot += wv;
            }
            for (int q = 0; q < pnPrev; ++q) U[tid*16 + q] = (float)(w64[q] / tot);
        }
        __syncthreads();
        // ---- P5: windowed bicubic apply, 1 thread per yx, 4 channels.
        //     term=fl(fl(h*wy)*wx), p outer asc, q inner asc, fl adds;
        //     zero taps outside window are exact +0.0 identities. ----
        {
            const double inv = 1.0 / (16.0 / (double)pnPrev);
            const int yx = tid, y = yx >> 4, x = yx & 15;
            double sy = ((double)y + 0.5) * inv - 0.5;
            double sx = ((double)x + 0.5) * inv - 0.5;
            int p0 = (int)floor(sy) - 1, q0 = (int)floor(sx) - 1;
            int pa = max(0, p0), pb = min(pnPrev - 1, p0 + 3);
            int qa = max(0, q0), qb = min(pnPrev - 1, q0 + 3);
            float acc0 = 0.f, acc1 = 0.f, acc2 = 0.f, acc3 = 0.f;
            for (int p = pa; p <= pb; ++p) {
                float wy = U[y*16 + p];
                for (int q = qa; q <= qb; ++q) {
                    float wx = U[x*16 + q];
                    const float* hp = &hs[(p*pnPrev + q)*4];
                    acc0 = __fadd_rn(acc0, __fmul_rn(__fmul_rn(hp[0], wy), wx));
                    acc1 = __fadd_rn(acc1, __fmul_rn(__fmul_rn(hp[1], wy), wx));
                    acc2 = __fadd_rn(acc2, __fmul_rn(__fmul_rn(hp[2], wy), wx));
                    acc3 = __fadd_rn(acc3, __fmul_rn(__fmul_rn(hp[3], wy), wx));
                }
            }
            float a4[4] = {acc0, acc1, acc2, acc3};
            #pragma unroll
            for (int cc = 0; cc < 4; ++cc) {
                float frv = __fsub_rn(fr[yx*5 + cc], a4[cc]);
                fr[yx*5 + cc] = frv;
                int go = b*8192 + (c0 + cc)*256 + yx;
                state[go] = frv;
                fhat[go] = (sIdx == 1) ? a4[cc] : __fadd_rn(fhat[go], a4[cc]);
            }
        }
        __syncthreads();
    }

    // ---- P7: area pool (np einsum order: fl(coef*f), h outer, w inner) + z write ----
    const int V = pn * pn;
    if (pn < 16) {
        if (tid < V) {
            int p = tid / pn, q = tid - p*pn;
            int sh = (p*16)/pn, eh = ((p+1)*16 + pn - 1)/pn;
            int sw = (q*16)/pn, ew = ((q+1)*16 + pn - 1)/pn;
            float Mh = (float)(1.0/(double)(eh - sh));
            float Mw = (float)(1.0/(double)(ew - sw));
            float coef = __fmul_rn(Mh, Mw);
            float a4[4] = {0.f, 0.f, 0.f, 0.f};
            for (int hh = sh; hh < eh; ++hh)
                for (int wy = sw; wy < ew; ++wy) {
                    const float* fp = &fr[(hh*16 + wy)*5];
                    #pragma unroll
                    for (int cc = 0; cc < 4; ++cc)
                        a4[cc] = __fadd_rn(a4[cc], __fmul_rn(coef, fp[cc]));
                }
            *(float4*)(zws + (size_t)((tid << 6) + b)*32 + c0) =
                make_float4(a4[0], a4[1], a4[2], a4[3]);
        }
    } else {
        const int yx = tid;
        *(float4*)(zws + (size_t)((yx << 6) + b)*32 + c0) =
            make_float4(fr[yx*5], fr[yx*5 + 1], fr[yx*5 + 2], fr[yx*5 + 3]);
    }
}

// ---------------- scan: SGPR emb rows, 2-code fused load+wait, 1 pair/lane --
// Round-5 lesson: the scan is latency-hiding-limited -> more waves, not more
// work per wave. 64 pairs per WG (1 per lane), grid doubles vs round 4
// (big scan: 2048 WGs = 8 WGs/CU target). Per 2-code step a wave issues
// ~180cy VALU vs ~200cy scalar wait; 6-7 resident waves/SIMD oversubscribe
// the SIMD ~3x -> waits hidden, VALU-issue-bound. VGPR ~40 (8 z-float4s).
// Scalar-path structure identical to validated rounds 3-4 (single asm
// statement: 4x s_load_dwordx16 + s_load_dwordx2 + s_waitcnt lgkmcnt(0); no
// scalar DMA outlives its statement -> no cross-statement liveness hazards).
// Per-code FMA chain order (dims ascending), d formula, per-wave ascending j
// (j before j+1, strict <), and (d,j)-lex cross-wave reduce (disjoint
// ascending wave ranges) are bit-identical to the validated version.
// N = V*64 is always a multiple of 64 -> no clamps, PB = V exactly.
typedef float f32x16 __attribute__((ext_vector_type(16)));
typedef float f32x2  __attribute__((ext_vector_type(2)));

#define SLOADW2(E0, E1, F0, F1, Q2, JS) { \
    const float* _pe = emb + ((size_t)(JS) << 5); \
    const float* _pq = esq + (JS); \
    asm volatile("s_load_dwordx16 %0, %5, 0x0\n\t" \
                 "s_load_dwordx16 %1, %5, 0x40\n\t" \
                 "s_load_dwordx16 %2, %5, 0x80\n\t" \
                 "s_load_dwordx16 %3, %5, 0xC0\n\t" \
                 "s_load_dwordx2  %4, %6, 0x0\n\t" \
                 "s_waitcnt lgkmcnt(0)" \
        : "=&s"(E0), "=&s"(E1), "=&s"(F0), "=&s"(F1), "=&s"(Q2) \
        : "s"(_pe), "s"(_pq)); }

// one 4-dim group for codes j (EV->acc0) and j+1 (FV->acc1) vs lane's pair Z:
// two independent ascending FMA chains (ILP), each bit-identical per code.
#define DOT2C(EV, FV, K, Z) { \
    acc0 = __fmaf_rn(EV[4*(K)+0], Z.x, acc0); acc1 = __fmaf_rn(FV[4*(K)+0], Z.x, acc1); \
    acc0 = __fmaf_rn(EV[4*(K)+1], Z.y, acc0); acc1 = __fmaf_rn(FV[4*(K)+1], Z.y, acc1); \
    acc0 = __fmaf_rn(EV[4*(K)+2], Z.z, acc0); acc1 = __fmaf_rn(FV[4*(K)+2], Z.z, acc1); \
    acc0 = __fmaf_rn(EV[4*(K)+3], Z.w, acc0); acc1 = __fmaf_rn(FV[4*(K)+3], Z.w, acc1); }

__global__ __launch_bounds__(256, 6) void vq_scan(
    const float* __restrict__ emb, const float* __restrict__ esq,
    const float* __restrict__ zws, float* __restrict__ psc, int* __restrict__ pix,
    int V, int ncbMask, int ncbShift, int CB)
{
    __shared__ float red_f[256];
    __shared__ int   red_i[256];

    const int tid  = threadIdx.x;
    const int cb   = blockIdx.x & ncbMask;
    const int pblk = blockIdx.x >> ncbShift;
    const int w    = tid >> 6, lane = tid & 63;

    const int pair = (pblk << 6) + lane;          // always < N (N = V*64)
    const float4* zp = (const float4*)(zws + (size_t)pair*32);
    float4 z0 = zp[0], z1 = zp[1], z2 = zp[2], z3 = zp[3];
    float4 z4 = zp[4], z5 = zp[5], z6 = zp[6], z7 = zp[7];
    float zsq = np_pw32(v4sq(z0),v4sq(z1),v4sq(z2),v4sq(z3),
                        v4sq(z4),v4sq(z5),v4sq(z6),v4sq(z7));

    // per-wave contiguous code range: j ascending within wave = first-index
    const int jchunk = cb * CB;
    const int pw     = CB >> 2;                   // codes per wave (even, >=8)
    const int w_u    = __builtin_amdgcn_readfirstlane(w);
    const int jbase  = jchunk + w_u * pw;         // always even

    float best = INFINITY; int bi = 0;
    for (int i = 0; i < pw; i += 2) {
        const int j = jbase + i;
        f32x16 e0, e1, f0, f1; f32x2 q2;
        SLOADW2(e0, e1, f0, f1, q2, j);
        float acc0 = 0.f, acc1 = 0.f;
        DOT2C(e0, f0, 0, z0) DOT2C(e0, f0, 1, z1) DOT2C(e0, f0, 2, z2) DOT2C(e0, f0, 3, z3)
        DOT2C(e1, f1, 0, z4) DOT2C(e1, f1, 1, z5) DOT2C(e1, f1, 2, z6) DOT2C(e1, f1, 3, z7)
        float d0 = __fsub_rn(__fadd_rn(zsq, q2[0]), __fmul_rn(2.0f, acc0));
        float d1 = __fsub_rn(__fadd_rn(zsq, q2[1]), __fmul_rn(2.0f, acc1));
        if (d0 < best) { best = d0; bi = j; }     // j before j+1: first-index
        if (d1 < best) { best = d1; bi = j + 1; }
    }

    red_f[w*64 + lane] = best;  red_i[w*64 + lane] = bi;
    __syncthreads();

    if (tid < 64) {
        const int p = (pblk << 6) + tid;
        float bb = INFINITY; int bij = 0x7fffffff;
        #pragma unroll
        for (int ww = 0; ww < 4; ++ww) {          // wave j-ranges disjoint: (d,j) lex
            float sc = red_f[ww*64 + tid];
            int   ji = red_i[ww*64 + tid];
            if (sc < bb || (sc == bb && ji < bij)) { bb = sc; bij = ji; }
        }
        psc[(size_t)p*(ncbMask + 1) + cb] = bb;
        pix[(size_t)p*(ncbMask + 1) + cb] = bij;
    }
}

__global__ __launch_bounds__(256) void vq_final(
    const float* __restrict__ emb, const float* __restrict__ fhat,
    const float* __restrict__ psc, const int* __restrict__ pix,
    float* __restrict__ out)
{
    __shared__ int idx_arr[256];
    const int tid = threadIdx.x;
    const int b = blockIdx.x;
    {   // combine last scale (NCB=8) partials, ascending cb = ascending j
        float best = INFINITY; int bi = 0;
        const size_t pb0 = (size_t)((tid << 6) + b) * 8;
        for (int ch = 0; ch < 8; ++ch) {
            float sc = psc[pb0 + ch];
            if (sc < best) { best = sc; bi = pix[pb0 + ch]; }
        }
        idx_arr[tid] = bi;
    }
    __syncthreads();
    // out = f_hat + h9 (channel-major matches out BCHW), coalesced
    for (int o = tid; o < 8192; o += 256) {
        int c = o >> 8, yx = o & 255;
        out[b*8192 + o] = __fadd_rn(fhat[(size_t)b*8192 + o],
                                    emb[(size_t)idx_arr[yx]*32 + c]);
    }
}

extern "C" void kernel_launch(void* const* d_in, const int* in_sizes, int n_in,
                              void* d_out, int out_size, void* d_ws, size_t ws_size,
                              hipStream_t stream) {
    const float* f   = (const float*)d_in[0];
    const float* emb = (const float*)d_in[1];
    float* ws  = (float*)d_ws;
    float* out = (float*)d_out;
    float* esq   = ws + WS_ESQ;
    float* state = ws + WS_STATE;
    float* fhatp = ws + WS_FHAT;
    float* zws   = ws + WS_Z;
    float* psc   = ws + WS_PSC;
    int*   pixp  = (int*)(ws + WS_PIX);
    static const int pns[10]  = {1, 2, 3, 4, 5, 6, 8, 10, 13, 16};
    static const int ncbl[10] = {7, 7, 6, 6, 5, 5, 4, 4, 3, 3};   // log2(NCB)

    for (int s = 0; s < 10; ++s) {
        int pn = pns[s], V = pn*pn, sh = ncbl[s];
        int PB = V;                                // 64 pairs per WG, N = V*64
        vq_apply<<<(s == 0) ? 528 : 512, 256, 0, stream>>>(
            f, emb, esq, state, fhatp, zws, psc, pixp,
            s, pn, s > 0 ? pns[s-1] : 0, s > 0 ? (1 << ncbl[s-1]) : 0);
        vq_scan<<<PB << sh, 256, 0, stream>>>(emb, esq, zws, psc, pixp,
                                              V, (1 << sh) - 1, sh, 4096 >> sh);
    }
    vq_final<<<64, 256, 0, stream>>>(emb, fhatp, psc, pixp, out);
}

// Round 7
// 389.705 us; speedup vs baseline: 1.1226x; 1.1226x over previous
//
#include <hip/hip_runtime.h>
#include <math.h>

// ws layout (floats):
//   esq   : [4096]
//   state : [64*8192]   f_rest, channel-major [b][c][yx]  (== f layout)
//   fhat  : [64*8192]   [b][c][yx]
//   z     : [16384][32] pair=(v<<6|b) rows
//   psc   : [131072]    pair*NCB+cb
//   pix   : [131072] int
#define WS_ESQ   0
#define WS_STATE 4096
#define WS_FHAT  (4096 + 524288)
#define WS_Z     (4096 + 2*524288)
#define WS_PSC   (4096 + 3*524288)
#define WS_PIX   (4096 + 3*524288 + 131072)

__device__ __forceinline__ float4 v4add(float4 a, float4 b) {
    return make_float4(__fadd_rn(a.x,b.x), __fadd_rn(a.y,b.y),
                       __fadd_rn(a.z,b.z), __fadd_rn(a.w,b.w));
}
__device__ __forceinline__ float4 v4sq(float4 a) {
    return make_float4(__fmul_rn(a.x,a.x), __fmul_rn(a.y,a.y),
                       __fmul_rn(a.z,a.z), __fmul_rn(a.w,a.w));
}
// numpy pairwise sum of 32 pre-rounded squares held in 8 float4s
__device__ __forceinline__ float np_pw32(float4 q0, float4 q1, float4 q2, float4 q3,
                                         float4 q4, float4 q5, float4 q6, float4 q7) {
    float4 rA = v4add(v4add(v4add(q0, q2), q4), q6);   // r[0..3]
    float4 rB = v4add(v4add(v4add(q1, q3), q5), q7);   // r[4..7]
    float l = __fadd_rn(__fadd_rn(rA.x, rA.y), __fadd_rn(rA.z, rA.w));
    float h = __fadd_rn(__fadd_rn(rB.x, rB.y), __fadd_rn(rB.z, rB.w));
    return __fadd_rn(l, h);
}

__device__ __forceinline__ double keys64(double x) {
    // jax keys cubic (a=-0.5)
    if (x < 1.0)      return ((1.5*x - 2.5)*x)*x + 1.0;
    else if (x < 2.0) return ((-0.5*x + 2.5)*x - 4.0)*x + 2.0;
    return 0.0;
}

// Apply kernel: 512 WGs = 64 b x 8 channel-slices of 4 (+16 esq WGs at s0).
// Combine prev partial argmins (2-stage, contiguous-ascending = first-index),
// gather h slice, bicubic-apply, persist state/fhat (channel-major), pool,
// write z rows. All fp32 sequences bit-identical to validated round-6 kernel.
__global__ __launch_bounds__(256) void vq_apply(
    const float* __restrict__ f, const float* __restrict__ emb,
    float* __restrict__ esq, float* __restrict__ state, float* __restrict__ fhat,
    float* __restrict__ zws, const float* __restrict__ psc, const int* __restrict__ pix,
    int sIdx, int pn, int pnPrev, int ncbPrev)
{
    __shared__ float fr[1280];      // f_rest slice [yx*5+cc]
    __shared__ float hs[676];       // h slice [v*4+cc]
    __shared__ int   idx_arr[176];
    __shared__ float U[256];        // bicubic weights [out][in], fp64->fp32 like jax
    __shared__ float red_f[1360];
    __shared__ int   red_i[1360];

    const int tid = threadIdx.x;
    const int wg  = blockIdx.x;
    if (wg >= 512) {                // s0 only: esq WGs
        int j = ((wg - 512) << 8) + tid;
        const float4* e4 = (const float4*)(emb + (size_t)j*32);
        esq[j] = np_pw32(v4sq(e4[0]),v4sq(e4[1]),v4sq(e4[2]),v4sq(e4[3]),
                         v4sq(e4[4]),v4sq(e4[5]),v4sq(e4[6]),v4sq(e4[7]));
        return;
    }
    const int b  = wg >> 3;
    const int c0 = (wg & 7) * 4;

    // ---- P1: load f_rest slice (channel-major, coalesced) ----
    const float* src = (sIdx <= 1) ? f : state;      // s0 never writes state: same layout
    for (int o = tid; o < 1024; o += 256) {
        int cc = o >> 8, yx = o & 255;
        fr[yx*5 + cc] = src[b*8192 + (c0 + cc)*256 + yx];
    }
    __syncthreads();

    if (sIdx > 0) {
        const int Vp = pnPrev * pnPrev;
        // ---- P2: combine prev partials, 2-stage (both contiguous ascending j) ----
        const int step = ncbPrev >> 3;
        for (int t = tid; t < Vp*8; t += 256) {
            int v = t >> 3, k = t & 7;
            const size_t base = (size_t)((v << 6) + b) * ncbPrev;
            float best = INFINITY; int bi = 0;
            for (int ch = k*step; ch < (k+1)*step; ++ch) {
                float sc = psc[base + ch];
                if (sc < best) { best = sc; bi = pix[base + ch]; }
            }
            red_f[t] = best; red_i[t] = bi;
        }
        __syncthreads();
        if (tid < Vp) {
            float best = INFINITY; int bi = 0;
            for (int k = 0; k < 8; ++k) {
                float sc = red_f[tid*8 + k];
                if (sc < best) { best = sc; bi = red_i[tid*8 + k]; }
            }
            idx_arr[tid] = bi;
        }
        __syncthreads();
        // ---- P3: gather h slice ----
        for (int t = tid; t < Vp*4; t += 256)
            hs[t] = emb[(size_t)idx_arr[t >> 2]*32 + c0 + (t & 3)];
        // ---- P4: bicubic weights in fp64 exactly like jax ----
        if (tid < 16) {
            double scl = 16.0 / (double)pnPrev;
            double inv = 1.0 / scl;
            double sp = ((double)tid + 0.5) * inv - 0.5;
            double w64[16]; double tot = 0.0;
            for (int q = 0; q < pnPrev; ++q) {
                double wv = keys64(fabs(sp - (double)q));
                w64[q] = wv; tot += wv;
            }
            for (int q = 0; q < pnPrev; ++q) U[tid*16 + q] = (float)(w64[q] / tot);
        }
        __syncthreads();
        // ---- P5: windowed bicubic apply, 1 thread per yx, 4 channels.
        //     term=fl(fl(h*wy)*wx), p outer asc, q inner asc, fl adds;
        //     zero taps outside window are exact +0.0 identities. ----
        {
            const double inv = 1.0 / (16.0 / (double)pnPrev);
            const int yx = tid, y = yx >> 4, x = yx & 15;
            double sy = ((double)y + 0.5) * inv - 0.5;
            double sx = ((double)x + 0.5) * inv - 0.5;
            int p0 = (int)floor(sy) - 1, q0 = (int)floor(sx) - 1;
            int pa = max(0, p0), pb = min(pnPrev - 1, p0 + 3);
            int qa = max(0, q0), qb = min(pnPrev - 1, q0 + 3);
            float acc0 = 0.f, acc1 = 0.f, acc2 = 0.f, acc3 = 0.f;
            for (int p = pa; p <= pb; ++p) {
                float wy = U[y*16 + p];
                for (int q = qa; q <= qb; ++q) {
                    float wx = U[x*16 + q];
                    const float* hp = &hs[(p*pnPrev + q)*4];
                    acc0 = __fadd_rn(acc0, __fmul_rn(__fmul_rn(hp[0], wy), wx));
                    acc1 = __fadd_rn(acc1, __fmul_rn(__fmul_rn(hp[1], wy), wx));
                    acc2 = __fadd_rn(acc2, __fmul_rn(__fmul_rn(hp[2], wy), wx));
                    acc3 = __fadd_rn(acc3, __fmul_rn(__fmul_rn(hp[3], wy), wx));
                }
            }
            float a4[4] = {acc0, acc1, acc2, acc3};
            #pragma unroll
            for (int cc = 0; cc < 4; ++cc) {
                float frv = __fsub_rn(fr[yx*5 + cc], a4[cc]);
                fr[yx*5 + cc] = frv;
                int go = b*8192 + (c0 + cc)*256 + yx;
                state[go] = frv;
                fhat[go] = (sIdx == 1) ? a4[cc] : __fadd_rn(fhat[go], a4[cc]);
            }
        }
        __syncthreads();
    }

    // ---- P7: area pool (np einsum order: fl(coef*f), h outer, w inner) + z write ----
    const int V = pn * pn;
    if (pn < 16) {
        if (tid < V) {
            int p = tid / pn, q = tid - p*pn;
            int sh = (p*16)/pn, eh = ((p+1)*16 + pn - 1)/pn;
            int sw = (q*16)/pn, ew = ((q+1)*16 + pn - 1)/pn;
            float Mh = (float)(1.0/(double)(eh - sh));
            float Mw = (float)(1.0/(double)(ew - sw));
            float coef = __fmul_rn(Mh, Mw);
            float a4[4] = {0.f, 0.f, 0.f, 0.f};
            for (int hh = sh; hh < eh; ++hh)
                for (int wy = sw; wy < ew; ++wy) {
                    const float* fp = &fr[(hh*16 + wy)*5];
                    #pragma unroll
                    for (int cc = 0; cc < 4; ++cc)
                        a4[cc] = __fadd_rn(a4[cc], __fmul_rn(coef, fp[cc]));
                }
            *(float4*)(zws + (size_t)((tid << 6) + b)*32 + c0) =
                make_float4(a4[0], a4[1], a4[2], a4[3]);
        }
    } else {
        const int yx = tid;
        *(float4*)(zws + (size_t)((yx << 6) + b)*32 + c0) =
            make_float4(fr[yx*5], fr[yx*5 + 1], fr[yx*5 + 2], fr[yx*5 + 3]);
    }
}

// ---------------- scan: SGPR emb rows, 2-code fused load+wait, 2 pairs/lane -
// Round-4 configuration (measured optimum of the pairs/lane axis: 4pl=67.6us,
// 2pl=64.9us, 1pl=92.6us). Single asm statement per step: 4x s_load_dwordx16
// + s_load_dwordx2 + s_waitcnt lgkmcnt(0); no scalar DMA outlives its
// statement -> no cross-statement liveness hazards.
// NEW vs round 4: cb-MAJOR grid decode (cb = wg/PB, pblk = wg%PB).
// Consecutive block ids now share the same 64KB emb chunk and advance j in
// near-lockstep, so co-resident WGs on a CU hit the per-CU scalar cache
// instead of all paying the ~200cy L2 trip each step. Pure index permutation:
// every (pblk, cb) covered exactly once; numerics untouched.
// FMA chain order, d formula, per-wave ascending j (j before j+1, strict <),
// and (d,j)-lex cross-wave reduce are bit-identical to the validated version.
typedef float f32x16 __attribute__((ext_vector_type(16)));
typedef float f32x2  __attribute__((ext_vector_type(2)));

#define SLOADW2(E0, E1, F0, F1, Q2, JS) { \
    const float* _pe = emb + ((size_t)(JS) << 5); \
    const float* _pq = esq + (JS); \
    asm volatile("s_load_dwordx16 %0, %5, 0x0\n\t" \
                 "s_load_dwordx16 %1, %5, 0x40\n\t" \
                 "s_load_dwordx16 %2, %5, 0x80\n\t" \
                 "s_load_dwordx16 %3, %5, 0xC0\n\t" \
                 "s_load_dwordx2  %4, %6, 0x0\n\t" \
                 "s_waitcnt lgkmcnt(0)" \
        : "=&s"(E0), "=&s"(E1), "=&s"(F0), "=&s"(F1), "=&s"(Q2) \
        : "s"(_pe), "s"(_pq)); }

#define DOT4S(EV, K, ZA, ZB) { \
    const float ex_ = EV[4*(K)+0], ey_ = EV[4*(K)+1]; \
    const float ez_ = EV[4*(K)+2], ew_ = EV[4*(K)+3]; \
    acc0 = __fmaf_rn(ex_, ZA.x, acc0); acc1 = __fmaf_rn(ex_, ZB.x, acc1); \
    acc0 = __fmaf_rn(ey_, ZA.y, acc0); acc1 = __fmaf_rn(ey_, ZB.y, acc1); \
    acc0 = __fmaf_rn(ez_, ZA.z, acc0); acc1 = __fmaf_rn(ez_, ZB.z, acc1); \
    acc0 = __fmaf_rn(ew_, ZA.w, acc0); acc1 = __fmaf_rn(ew_, ZB.w, acc1); }

#define CODE_STEP(E0, E1, SQ, J) { \
    float acc0 = 0.f, acc1 = 0.f; \
    DOT4S(E0, 0, a0, b0) DOT4S(E0, 1, a1, b1) DOT4S(E0, 2, a2, b2) DOT4S(E0, 3, a3, b3) \
    DOT4S(E1, 0, a4, b4) DOT4S(E1, 1, a5, b5) DOT4S(E1, 2, a6, b6) DOT4S(E1, 3, a7, b7) \
    float d0 = __fsub_rn(__fadd_rn(zsq0, SQ), __fmul_rn(2.0f, acc0)); \
    float d1 = __fsub_rn(__fadd_rn(zsq1, SQ), __fmul_rn(2.0f, acc1)); \
    if (d0 < best0) { best0 = d0; bi0 = (J); } \
    if (d1 < best1) { best1 = d1; bi1 = (J); } }

__global__ __launch_bounds__(256, 4) void vq_scan(
    const float* __restrict__ emb, const float* __restrict__ esq,
    const float* __restrict__ zws, float* __restrict__ psc, int* __restrict__ pix,
    int V, int ncbMask, int PB, int CB)
{
    __shared__ float red_f[512];
    __shared__ int   red_i[512];

    const int tid  = threadIdx.x;
    const int cb   = blockIdx.x / PB;       // cb-major: neighbors share emb chunk
    const int pblk = blockIdx.x - cb * PB;
    const int w    = tid >> 6, lane = tid & 63;
    const int N    = V << 6;

    const int pair0 = (pblk << 7) + lane;
    const int p0c = min(pair0, N - 1), p1c = min(pair0 + 64, N - 1);
    const float4* za = (const float4*)(zws + (size_t)p0c*32);
    const float4* zb = (const float4*)(zws + (size_t)p1c*32);
    float4 a0 = za[0], a1 = za[1], a2 = za[2], a3 = za[3];
    float4 a4 = za[4], a5 = za[5], a6 = za[6], a7 = za[7];
    float4 b0 = zb[0], b1 = zb[1], b2 = zb[2], b3 = zb[3];
    float4 b4 = zb[4], b5 = zb[5], b6 = zb[6], b7 = zb[7];
    float zsq0 = np_pw32(v4sq(a0),v4sq(a1),v4sq(a2),v4sq(a3),
                         v4sq(a4),v4sq(a5),v4sq(a6),v4sq(a7));
    float zsq1 = np_pw32(v4sq(b0),v4sq(b1),v4sq(b2),v4sq(b3),
                         v4sq(b4),v4sq(b5),v4sq(b6),v4sq(b7));

    // per-wave contiguous code range: j ascending within wave = first-index
    const int jchunk = cb * CB;
    const int pw     = CB >> 2;                       // codes per wave (even, >=8)
    const int w_u    = __builtin_amdgcn_readfirstlane(w);
    const int jbase  = jchunk + w_u * pw;             // always even

    float best0 = INFINITY, best1 = INFINITY; int bi0 = 0, bi1 = 0;
    for (int i = 0; i < pw; i += 2) {
        const int j = jbase + i;
        f32x16 e0, e1, f0, f1; f32x2 q2;
        SLOADW2(e0, e1, f0, f1, q2, j);
        const float q0 = q2[0], q1 = q2[1];
        CODE_STEP(e0, e1, q0, j);
        CODE_STEP(f0, f1, q1, j + 1);
    }

    red_f[w*128 + lane]      = best0;  red_i[w*128 + lane]      = bi0;
    red_f[w*128 + 64 + lane] = best1;  red_i[w*128 + 64 + lane] = bi1;
    __syncthreads();

    if (tid < 128) {
        const int p = (pblk << 7) + tid;
        if (p < N) {
            float bb = INFINITY; int bi = 0x7fffffff;
            #pragma unroll
            for (int ww = 0; ww < 4; ++ww) {     // wave j-ranges disjoint: (d,j) lex
                float sc = red_f[ww*128 + tid];
                int   ji = red_i[ww*128 + tid];
                if (sc < bb || (sc == bb && ji < bi)) { bb = sc; bi = ji; }
            }
            psc[(size_t)p*(ncbMask + 1) + cb] = bb;
            pix[(size_t)p*(ncbMask + 1) + cb] = bi;
        }
    }
}

__global__ __launch_bounds__(256) void vq_final(
    const float* __restrict__ emb, const float* __restrict__ fhat,
    const float* __restrict__ psc, const int* __restrict__ pix,
    float* __restrict__ out)
{
    __shared__ int idx_arr[256];
    const int tid = threadIdx.x;
    const int b = blockIdx.x;
    {   // combine last scale (NCB=8) partials, ascending cb = ascending j
        float best = INFINITY; int bi = 0;
        const size_t pb0 = (size_t)((tid << 6) + b) * 8;
        for (int ch = 0; ch < 8; ++ch) {
            float sc = psc[pb0 + ch];
            if (sc < best) { best = sc; bi = pix[pb0 + ch]; }
        }
        idx_arr[tid] = bi;
    }
    __syncthreads();
    // out = f_hat + h9 (channel-major matches out BCHW), coalesced
    for (int o = tid; o < 8192; o += 256) {
        int c = o >> 8, yx = o & 255;
        out[b*8192 + o] = __fadd_rn(fhat[(size_t)b*8192 + o],
                                    emb[(size_t)idx_arr[yx]*32 + c]);
    }
}

extern "C" void kernel_launch(void* const* d_in, const int* in_sizes, int n_in,
                              void* d_out, int out_size, void* d_ws, size_t ws_size,
                              hipStream_t stream) {
    const float* f   = (const float*)d_in[0];
    const float* emb = (const float*)d_in[1];
    float* ws  = (float*)d_ws;
    float* out = (float*)d_out;
    float* esq   = ws + WS_ESQ;
    float* state = ws + WS_STATE;
    float* fhatp = ws + WS_FHAT;
    float* zws   = ws + WS_Z;
    float* psc   = ws + WS_PSC;
    int*   pixp  = (int*)(ws + WS_PIX);
    static const int pns[10]  = {1, 2, 3, 4, 5, 6, 8, 10, 13, 16};
    static const int ncbl[10] = {7, 7, 6, 6, 5, 5, 4, 4, 3, 3};   // log2(NCB)

    for (int s = 0; s < 10; ++s) {
        int pn = pns[s], V = pn*pn, sh = ncbl[s];
        int PB = ((V << 6) + 127) >> 7;
        vq_apply<<<(s == 0) ? 528 : 512, 256, 0, stream>>>(
            f, emb, esq, state, fhatp, zws, psc, pixp,
            s, pn, s > 0 ? pns[s-1] : 0, s > 0 ? (1 << ncbl[s-1]) : 0);
        vq_scan<<<PB << sh, 256, 0, stream>>>(emb, esq, zws, psc, pixp,
                                              V, (1 << sh) - 1, PB, 4096 >> sh);
    }
    vq_final<<<64, 256, 0, stream>>>(emb, fhatp, psc, pixp, out);
}

// Round 8
// 368.356 us; speedup vs baseline: 1.1877x; 1.0580x over previous
//
#include <hip/hip_runtime.h>
#include <math.h>

// ws layout (floats):
//   esq   : [4096]
//   state : [64*8192]   f_rest, channel-major [b][c][yx]  (== f layout)
//   fhat  : [64*8192]   [b][c][yx]
//   z     : [16384][32] pair=(v<<6|b) rows
//   keys  : [2][16384] u64 (in old psc region) — packed (mono(d)<<32)|j per pair
#define WS_ESQ   0
#define WS_STATE 4096
#define WS_FHAT  (4096 + 524288)
#define WS_Z     (4096 + 2*524288)
#define WS_PSC   (4096 + 3*524288)

__device__ __forceinline__ float4 v4add(float4 a, float4 b) {
    return make_float4(__fadd_rn(a.x,b.x), __fadd_rn(a.y,b.y),
                       __fadd_rn(a.z,b.z), __fadd_rn(a.w,b.w));
}
__device__ __forceinline__ float4 v4sq(float4 a) {
    return make_float4(__fmul_rn(a.x,a.x), __fmul_rn(a.y,a.y),
                       __fmul_rn(a.z,a.z), __fmul_rn(a.w,a.w));
}
// numpy pairwise sum of 32 pre-rounded squares held in 8 float4s
__device__ __forceinline__ float np_pw32(float4 q0, float4 q1, float4 q2, float4 q3,
                                         float4 q4, float4 q5, float4 q6, float4 q7) {
    float4 rA = v4add(v4add(v4add(q0, q2), q4), q6);   // r[0..3]
    float4 rB = v4add(v4add(v4add(q1, q3), q5), q7);   // r[4..7]
    float l = __fadd_rn(__fadd_rn(rA.x, rA.y), __fadd_rn(rA.z, rA.w));
    float h = __fadd_rn(__fadd_rn(rB.x, rB.y), __fadd_rn(rB.z, rB.w));
    return __fadd_rn(l, h);
}

__device__ __forceinline__ double keys64(double x) {
    // jax keys cubic (a=-0.5)
    if (x < 1.0)      return ((1.5*x - 2.5)*x)*x + 1.0;
    else if (x < 2.0) return ((-0.5*x + 2.5)*x - 4.0)*x + 2.0;
    return 0.0;
}

// Apply kernel: 512 WGs = 64 b x 8 channel-slices of 4 (+16 esq WGs at s0).
// Prev-scale argmin now comes straight from the packed atomic key (low 32
// bits) — exact (d,j)-lex winner, identical to the old 2-stage combine.
// Slice-0 WGs also init THIS scale's key buffer (double-buffered by s&1, so
// no read/write hazard with the prev buffer). All fp32 sequences (bicubic,
// pool) bit-identical to the validated kernel.
__global__ __launch_bounds__(256) void vq_apply(
    const float* __restrict__ f, const float* __restrict__ emb,
    float* __restrict__ esq, float* __restrict__ state, float* __restrict__ fhat,
    float* __restrict__ zws, const unsigned long long* __restrict__ keysPrev,
    unsigned long long* __restrict__ keysCur,
    int sIdx, int pn, int pnPrev)
{
    __shared__ float fr[1280];      // f_rest slice [yx*5+cc]
    __shared__ float hs[676];       // h slice [v*4+cc]
    __shared__ int   idx_arr[176];
    __shared__ float U[256];        // bicubic weights [out][in], fp64->fp32 like jax

    const int tid = threadIdx.x;
    const int wg  = blockIdx.x;
    if (wg >= 512) {                // s0 only: esq WGs
        int j = ((wg - 512) << 8) + tid;
        const float4* e4 = (const float4*)(emb + (size_t)j*32);
        esq[j] = np_pw32(v4sq(e4[0]),v4sq(e4[1]),v4sq(e4[2]),v4sq(e4[3]),
                         v4sq(e4[4]),v4sq(e4[5]),v4sq(e4[6]),v4sq(e4[7]));
        return;
    }
    const int b  = wg >> 3;
    const int c0 = (wg & 7) * 4;

    // init this scale's keys (slice-0 WG per b); scan launches after apply
    // completes, so no intra-kernel ordering needed.
    if ((wg & 7) == 0) {
        const int V = pn * pn;
        for (int v = tid; v < V; v += 256) keysCur[(v << 6) + b] = ~0ull;
    }

    // ---- P1: load f_rest slice (channel-major, coalesced) ----
    const float* src = (sIdx <= 1) ? f : state;      // s0 never writes state: same layout
    for (int o = tid; o < 1024; o += 256) {
        int cc = o >> 8, yx = o & 255;
        fr[yx*5 + cc] = src[b*8192 + (c0 + cc)*256 + yx];
    }
    __syncthreads();

    if (sIdx > 0) {
        const int Vp = pnPrev * pnPrev;
        // ---- P2: read prev argmin from packed key (exact lex winner) ----
        if (tid < Vp)
            idx_arr[tid] = (int)(keysPrev[((size_t)tid << 6) + b] & 0xffffffffu);
        __syncthreads();
        // ---- P3: gather h slice ----
        for (int t = tid; t < Vp*4; t += 256)
            hs[t] = emb[(size_t)idx_arr[t >> 2]*32 + c0 + (t & 3)];
        // ---- P4: bicubic weights in fp64 exactly like jax ----
        if (tid < 16) {
            double scl = 16.0 / (double)pnPrev;
            double inv = 1.0 / scl;
            double sp = ((double)tid + 0.5) * inv - 0.5;
            double w64[16]; double tot = 0.0;
            for (int q = 0; q < pnPrev; ++q) {
                double wv = keys64(fabs(sp - (double)q));
                w64[q] = wv; tot += wv;
            }
            for (int q = 0; q < pnPrev; ++q) U[tid*16 + q] = (float)(w64[q] / tot);
        }
        __syncthreads();
        // ---- P5: windowed bicubic apply, 1 thread per yx, 4 channels.
        //     term=fl(fl(h*wy)*wx), p outer asc, q inner asc, fl adds;
        //     zero taps outside window are exact +0.0 identities. ----
        {
            const double inv = 1.0 / (16.0 / (double)pnPrev);
            const int yx = tid, y = yx >> 4, x = yx & 15;
            double sy = ((double)y + 0.5) * inv - 0.5;
            double sx = ((double)x + 0.5) * inv - 0.5;
            int p0 = (int)floor(sy) - 1, q0 = (int)floor(sx) - 1;
            int pa = max(0, p0), pb = min(pnPrev - 1, p0 + 3);
            int qa = max(0, q0), qb = min(pnPrev - 1, q0 + 3);
            float acc0 = 0.f, acc1 = 0.f, acc2 = 0.f, acc3 = 0.f;
            for (int p = pa; p <= pb; ++p) {
                float wy = U[y*16 + p];
                for (int q = qa; q <= qb; ++q) {
                    float wx = U[x*16 + q];
                    const float* hp = &hs[(p*pnPrev + q)*4];
                    acc0 = __fadd_rn(acc0, __fmul_rn(__fmul_rn(hp[0], wy), wx));
                    acc1 = __fadd_rn(acc1, __fmul_rn(__fmul_rn(hp[1], wy), wx));
                    acc2 = __fadd_rn(acc2, __fmul_rn(__fmul_rn(hp[2], wy), wx));
                    acc3 = __fadd_rn(acc3, __fmul_rn(__fmul_rn(hp[3], wy), wx));
                }
            }
            float a4[4] = {acc0, acc1, acc2, acc3};
            #pragma unroll
            for (int cc = 0; cc < 4; ++cc) {
                float frv = __fsub_rn(fr[yx*5 + cc], a4[cc]);
                fr[yx*5 + cc] = frv;
                int go = b*8192 + (c0 + cc)*256 + yx;
                state[go] = frv;
                fhat[go] = (sIdx == 1) ? a4[cc] : __fadd_rn(fhat[go], a4[cc]);
            }
        }
        __syncthreads();
    }

    // ---- P7: area pool (np einsum order: fl(coef*f), h outer, w inner) + z write ----
    const int V = pn * pn;
    if (pn < 16) {
        if (tid < V) {
            int p = tid / pn, q = tid - p*pn;
            int sh = (p*16)/pn, eh = ((p+1)*16 + pn - 1)/pn;
            int sw = (q*16)/pn, ew = ((q+1)*16 + pn - 1)/pn;
            float Mh = (float)(1.0/(double)(eh - sh));
            float Mw = (float)(1.0/(double)(ew - sw));
            float coef = __fmul_rn(Mh, Mw);
            float a4[4] = {0.f, 0.f, 0.f, 0.f};
            for (int hh = sh; hh < eh; ++hh)
                for (int wy = sw; wy < ew; ++wy) {
                    const float* fp = &fr[(hh*16 + wy)*5];
                    #pragma unroll
                    for (int cc = 0; cc < 4; ++cc)
                        a4[cc] = __fadd_rn(a4[cc], __fmul_rn(coef, fp[cc]));
                }
            *(float4*)(zws + (size_t)((tid << 6) + b)*32 + c0) =
                make_float4(a4[0], a4[1], a4[2], a4[3]);
        }
    } else {
        const int yx = tid;
        *(float4*)(zws + (size_t)((yx << 6) + b)*32 + c0) =
            make_float4(fr[yx*5], fr[yx*5 + 1], fr[yx*5 + 2], fr[yx*5 + 3]);
    }
}

// ---------------- scan: SGPR emb rows, 2 pairs/lane, atomic lex-min merge ---
// Per-WG numerics identical to validated rounds 4/7: single asm statement per
// 2-code step (4x s_load_dwordx16 + s_load_dwordx2 + s_waitcnt lgkmcnt(0); no
// scalar DMA outlives its statement), per-wave ascending j, 4-wave (d,j)-lex
// LDS reduce. NEW: the cross-chunk combine is a device-scope u64 atomicMin on
// key = (mono(d)<<32)|j, where mono() is the exact order-preserving
// float->u32 map — winner identical to sequential first-index combine (only
// +-0.0 ties could differ; distances are never exactly 0). This decouples WG
// count from the old psc chunk layout: grids of 1300-2700 WGs per scale fill
// the ~7 WGs/CU residency cap (round-7 counters: grid 4/CU was the limiter,
// VALUBusy 53% at 30% occupancy).
typedef float f32x16 __attribute__((ext_vector_type(16)));
typedef float f32x2  __attribute__((ext_vector_type(2)));

#define SLOADW2(E0, E1, F0, F1, Q2, JS) { \
    const float* _pe = emb + ((size_t)(JS) << 5); \
    const float* _pq = esq + (JS); \
    asm volatile("s_load_dwordx16 %0, %5, 0x0\n\t" \
                 "s_load_dwordx16 %1, %5, 0x40\n\t" \
                 "s_load_dwordx16 %2, %5, 0x80\n\t" \
                 "s_load_dwordx16 %3, %5, 0xC0\n\t" \
                 "s_load_dwordx2  %4, %6, 0x0\n\t" \
                 "s_waitcnt lgkmcnt(0)" \
        : "=&s"(E0), "=&s"(E1), "=&s"(F0), "=&s"(F1), "=&s"(Q2) \
        : "s"(_pe), "s"(_pq)); }

#define DOT4S(EV, K, ZA, ZB) { \
    const float ex_ = EV[4*(K)+0], ey_ = EV[4*(K)+1]; \
    const float ez_ = EV[4*(K)+2], ew_ = EV[4*(K)+3]; \
    acc0 = __fmaf_rn(ex_, ZA.x, acc0); acc1 = __fmaf_rn(ex_, ZB.x, acc1); \
    acc0 = __fmaf_rn(ey_, ZA.y, acc0); acc1 = __fmaf_rn(ey_, ZB.y, acc1); \
    acc0 = __fmaf_rn(ez_, ZA.z, acc0); acc1 = __fmaf_rn(ez_, ZB.z, acc1); \
    acc0 = __fmaf_rn(ew_, ZA.w, acc0); acc1 = __fmaf_rn(ew_, ZB.w, acc1); }

#define CODE_STEP(E0, E1, SQ, J) { \
    float acc0 = 0.f, acc1 = 0.f; \
    DOT4S(E0, 0, a0, b0) DOT4S(E0, 1, a1, b1) DOT4S(E0, 2, a2, b2) DOT4S(E0, 3, a3, b3) \
    DOT4S(E1, 0, a4, b4) DOT4S(E1, 1, a5, b5) DOT4S(E1, 2, a6, b6) DOT4S(E1, 3, a7, b7) \
    float d0 = __fsub_rn(__fadd_rn(zsq0, SQ), __fmul_rn(2.0f, acc0)); \
    float d1 = __fsub_rn(__fadd_rn(zsq1, SQ), __fmul_rn(2.0f, acc1)); \
    if (d0 < best0) { best0 = d0; bi0 = (J); } \
    if (d1 < best1) { best1 = d1; bi1 = (J); } }

__global__ __launch_bounds__(256, 4) void vq_scan(
    const float* __restrict__ emb, const float* __restrict__ esq,
    const float* __restrict__ zws, unsigned long long* __restrict__ keys,
    int V, int PB, int CB)
{
    __shared__ float red_f[512];
    __shared__ int   red_i[512];

    const int tid  = threadIdx.x;
    const int cb   = blockIdx.x / PB;       // cb-major: neighbors share emb chunk
    const int pblk = blockIdx.x - cb * PB;
    const int w    = tid >> 6, lane = tid & 63;
    const int N    = V << 6;

    const int pair0 = (pblk << 7) + lane;
    const int p0c = min(pair0, N - 1), p1c = min(pair0 + 64, N - 1);
    const float4* za = (const float4*)(zws + (size_t)p0c*32);
    const float4* zb = (const float4*)(zws + (size_t)p1c*32);
    float4 a0 = za[0], a1 = za[1], a2 = za[2], a3 = za[3];
    float4 a4 = za[4], a5 = za[5], a6 = za[6], a7 = za[7];
    float4 b0 = zb[0], b1 = zb[1], b2 = zb[2], b3 = zb[3];
    float4 b4 = zb[4], b5 = zb[5], b6 = zb[6], b7 = zb[7];
    float zsq0 = np_pw32(v4sq(a0),v4sq(a1),v4sq(a2),v4sq(a3),
                         v4sq(a4),v4sq(a5),v4sq(a6),v4sq(a7));
    float zsq1 = np_pw32(v4sq(b0),v4sq(b1),v4sq(b2),v4sq(b3),
                         v4sq(b4),v4sq(b5),v4sq(b6),v4sq(b7));

    // per-wave contiguous code range: j ascending within wave = first-index
    const int jchunk = cb * CB;
    const int pw     = CB >> 2;                       // codes per wave (even, >=4)
    const int w_u    = __builtin_amdgcn_readfirstlane(w);
    const int jbase  = jchunk + w_u * pw;             // always even

    float best0 = INFINITY, best1 = INFINITY; int bi0 = 0, bi1 = 0;
    for (int i = 0; i < pw; i += 2) {
        const int j = jbase + i;
        f32x16 e0, e1, f0, f1; f32x2 q2;
        SLOADW2(e0, e1, f0, f1, q2, j);
        const float q0 = q2[0], q1 = q2[1];
        CODE_STEP(e0, e1, q0, j);
        CODE_STEP(f0, f1, q1, j + 1);
    }

    red_f[w*128 + lane]      = best0;  red_i[w*128 + lane]      = bi0;
    red_f[w*128 + 64 + lane] = best1;  red_i[w*128 + 64 + lane] = bi1;
    __syncthreads();

    if (tid < 128) {
        const int p = (pblk << 7) + tid;
        if (p < N) {
            float bb = INFINITY; int bi = 0x7fffffff;
            #pragma unroll
            for (int ww = 0; ww < 4; ++ww) {     // wave j-ranges disjoint: (d,j) lex
                float sc = red_f[ww*128 + tid];
                int   ji = red_i[ww*128 + tid];
                if (sc < bb || (sc == bb && ji < bi)) { bb = sc; bi = ji; }
            }
            // exact order-preserving float->u32 map, then global (d,j)-lex
            // min via device-scope u64 atomicMin
            unsigned u  = __float_as_uint(bb);
            unsigned mu = (u & 0x80000000u) ? ~u : (u | 0x80000000u);
            unsigned long long key =
                ((unsigned long long)mu << 32) | (unsigned long long)(unsigned)bi;
            atomicMin(&keys[p], key);
        }
    }
}

__global__ __launch_bounds__(256) void vq_final(
    const float* __restrict__ emb, const float* __restrict__ fhat,
    const unsigned long long* __restrict__ keys,
    float* __restrict__ out)
{
    __shared__ int idx_arr[256];
    const int tid = threadIdx.x;
    const int b = blockIdx.x;
    idx_arr[tid] = (int)(keys[((size_t)tid << 6) + b] & 0xffffffffu);
    __syncthreads();
    // out = f_hat + h9 (channel-major matches out BCHW), coalesced
    for (int o = tid; o < 8192; o += 256) {
        int c = o >> 8, yx = o & 255;
        out[b*8192 + o] = __fadd_rn(fhat[(size_t)b*8192 + o],
                                    emb[(size_t)idx_arr[yx]*32 + c]);
    }
}

extern "C" void kernel_launch(void* const* d_in, const int* in_sizes, int n_in,
                              void* d_out, int out_size, void* d_ws, size_t ws_size,
                              hipStream_t stream) {
    const float* f   = (const float*)d_in[0];
    const float* emb = (const float*)d_in[1];
    float* ws  = (float*)d_ws;
    float* out = (float*)d_out;
    float* esq   = ws + WS_ESQ;
    float* state = ws + WS_STATE;
    float* fhatp = ws + WS_FHAT;
    float* zws   = ws + WS_Z;
    unsigned long long* keysA = (unsigned long long*)(ws + WS_PSC);  // [2][16384]
    static const int pns[10] = {1, 2, 3, 4, 5, 6, 8, 10, 13, 16};
    static const int cbs[10] = {16, 16, 16, 16, 32, 32, 64, 128, 128, 256};

    for (int s = 0; s < 10; ++s) {
        int pn = pns[s], V = pn*pn, CB = cbs[s];
        int NC = 4096 / CB;
        int PB = ((V << 6) + 127) >> 7;
        unsigned long long* keysCur  = keysA + (size_t)(s & 1) * 16384;
        unsigned long long* keysPrev = keysA + (size_t)((s & 1) ^ 1) * 16384;
        vq_apply<<<(s == 0) ? 528 : 512, 256, 0, stream>>>(
            f, emb, esq, state, fhatp, zws, keysPrev, keysCur,
            s, pn, s > 0 ? pns[s-1] : 0);
        vq_scan<<<PB * NC, 256, 0, stream>>>(emb, esq, zws, keysCur, V, PB, CB);
    }
    vq_final<<<64, 256, 0, stream>>>(emb, fhatp, keysA + 16384, out);
}